// Round 6
// baseline (351.136 us; speedup 1.0000x reference)
//
#include <hip/hip_runtime.h>

#define NB 16
#define NN 300000
#define PRE 2000
#define POST 1000

typedef unsigned long long ull;

// ---------- workspace layout (bytes) ----------
static const size_t OFF_HIST1   = 0;                       // 16*1024*4 = 65536
static const size_t OFF_HIST2   = 65536;                   // 16*2048*4 = 131072
static const size_t OFF_HIST3   = 196608;                  // 131072
static const size_t OFF_CANDCNT = 327680;                  // 64 (pad 256)
static const size_t OFF_EQCNT   = 327936;                  // 64 (pad 256)
static const size_t OFF_BITMAP  = 328192;                  // 16*32*8 = 4096
static const size_t OFF_B1      = 332288;
static const size_t OFF_NEED1   = 332544;
static const size_t OFF_B2      = 332800;
static const size_t OFF_NEED2   = 333056;
static const size_t OFF_B3      = 333312;
static const size_t OFF_NEED3   = 333568;
static const size_t OFF_NVALID  = 333824;                  // 64 (pad 256) — atomically accumulated, must be zeroed
static const size_t ZERO_BYTES  = 334080;                  // memset region
static const size_t OFF_CAND    = 334080;                  // 16*2048*4 = 131072
static const size_t OFF_EQBUF   = 465152;                  // 16*8192*4 = 524288
static const size_t OFF_KEYS    = 989440;                  // 16*2048*8 = 262144
static const size_t OFF_BOXTMP  = 1251584;                 // 16*2048*16 = 524288
static const size_t OFF_SORTED  = 1775872;                 // 16*2000*16 = 512000
static const size_t OFF_MASK    = 2287872;                 // 16*2000*32*8 = 8192000

__device__ __forceinline__ unsigned f2u(float f){
  unsigned b = __float_as_uint(f);
  return (b & 0x80000000u) ? ~b : (b | 0x80000000u);
}

// ---------- pass 1 histogram: top 10 bits (8 replicated LDS copies) ----------
#define H1REP 8
#define H1STRIDE 1025
__global__ void k_hist1(const float* __restrict__ cls, unsigned* __restrict__ hist){
  __shared__ unsigned h[H1REP * H1STRIDE];
  int img = blockIdx.y;
  for (int i = threadIdx.x; i < H1REP * H1STRIDE; i += blockDim.x) h[i] = 0;
  __syncthreads();
  const float* p = cls + (size_t)img * NN;
  int stride = gridDim.x * blockDim.x;
  unsigned rep = (threadIdx.x & (H1REP - 1)) * H1STRIDE;
  for (int i = blockIdx.x * blockDim.x + threadIdx.x; i < NN; i += stride)
    atomicAdd(&h[rep + (f2u(p[i]) >> 22)], 1u);
  __syncthreads();
  unsigned* g = hist + img * 1024;
  for (int i = threadIdx.x; i < 1024; i += blockDim.x){
    unsigned v = 0;
    for (int r = 0; r < H1REP; r++) v += h[r * H1STRIDE + i];
    if (v) atomicAdd(&g[i], v);
  }
}

// ---------- generic descending rank-select over a histogram ----------
__global__ void k_scan(const unsigned* __restrict__ hist, int bins,
                       const unsigned* __restrict__ tgt, unsigned K0,
                       unsigned* __restrict__ outBin, unsigned* __restrict__ outNeed){
  int img = blockIdx.x;
  int t = threadIdx.x;
  const unsigned* hh = hist + img * bins;
  unsigned K = tgt ? tgt[img] : K0;
  int per = bins >> 8;
  unsigned s = 0;
  for (int q = 0; q < per; q++) s += hh[bins - 1 - (t * per + q)];
  __shared__ unsigned arr[256];
  arr[t] = s;
  __syncthreads();
  for (int off = 1; off < 256; off <<= 1){
    unsigned v = (t >= off) ? arr[t - off] : 0u;
    __syncthreads();
    arr[t] += v;
    __syncthreads();
  }
  unsigned incl = arr[t], excl = incl - s;
  if (excl < K && K <= incl){
    unsigned c = excl;
    for (int q = 0; q < per; q++){
      int b = bins - 1 - (t * per + q);
      unsigned cnt = hh[b];
      if (c + cnt >= K){ outBin[img] = (unsigned)b; outNeed[img] = K - c; break; }
      c += cnt;
    }
  }
}

// ---------- pass 2 histogram: bits 21..11 within bin b1 ----------
__global__ void k_hist2(const float* __restrict__ cls, const unsigned* __restrict__ b1,
                        unsigned* __restrict__ hist){
  int img = blockIdx.y;
  unsigned bb1 = b1[img];
  const float* p = cls + (size_t)img * NN;
  unsigned* g = hist + img * 2048;
  int stride = gridDim.x * blockDim.x;
  for (int i = blockIdx.x * blockDim.x + threadIdx.x; i < NN; i += stride){
    unsigned u = f2u(p[i]);
    if ((u >> 22) == bb1) atomicAdd(&g[(u >> 11) & 0x7FFu], 1u);
  }
}

// ---------- pass 3 histogram: bits 10..0 within (b1,b2) ----------
__global__ void k_hist3(const float* __restrict__ cls, const unsigned* __restrict__ b1,
                        const unsigned* __restrict__ b2, unsigned* __restrict__ hist){
  int img = blockIdx.y;
  unsigned pref = (b1[img] << 11) | b2[img];
  const float* p = cls + (size_t)img * NN;
  unsigned* g = hist + img * 2048;
  int stride = gridDim.x * blockDim.x;
  for (int i = blockIdx.x * blockDim.x + threadIdx.x; i < NN; i += stride){
    unsigned u = f2u(p[i]);
    if ((u >> 11) == pref) atomicAdd(&g[u & 0x7FFu], 1u);
  }
}

// ---------- compaction: u > T -> cand ; u == T -> eqbuf (LDS-aggregated) ----------
__global__ void k_compact(const float* __restrict__ cls, const unsigned* __restrict__ b1,
                          const unsigned* __restrict__ b2, const unsigned* __restrict__ b3,
                          unsigned* __restrict__ cand, unsigned* __restrict__ candCnt,
                          unsigned* __restrict__ eqbuf, unsigned* __restrict__ eqCnt){
  __shared__ unsigned lc[1024];
  __shared__ unsigned le[256];
  __shared__ unsigned lcn, len_, baseC, baseE;
  int img = blockIdx.y;
  if (threadIdx.x == 0){ lcn = 0; len_ = 0; }
  __syncthreads();
  unsigned T = (b1[img] << 22) | (b2[img] << 11) | b3[img];
  const float* p = cls + (size_t)img * NN;
  int stride = gridDim.x * blockDim.x;
  for (int i = blockIdx.x * blockDim.x + threadIdx.x; i < NN; i += stride){
    unsigned u = f2u(p[i]);
    if (u > T){
      unsigned pos = atomicAdd(&lcn, 1u);
      if (pos < 1024u) lc[pos] = (unsigned)i;
      else { unsigned g = atomicAdd(&candCnt[img], 1u); if (g < 2048u) cand[img * 2048 + g] = (unsigned)i; }
    } else if (u == T){
      unsigned pos = atomicAdd(&len_, 1u);
      if (pos < 256u) le[pos] = (unsigned)i;
      else { unsigned g = atomicAdd(&eqCnt[img], 1u); if (g < 8192u) eqbuf[img * 8192 + g] = (unsigned)i; }
    }
  }
  __syncthreads();
  unsigned nc = lcn < 1024u ? lcn : 1024u;
  unsigned ne = len_ < 256u ? len_ : 256u;
  if (threadIdx.x == 0){
    if (nc) baseC = atomicAdd(&candCnt[img], nc);
    if (ne) baseE = atomicAdd(&eqCnt[img], ne);
  }
  __syncthreads();
  for (unsigned t = threadIdx.x; t < nc; t += blockDim.x){
    unsigned g = baseC + t;
    if (g < 2048u) cand[img * 2048 + g] = lc[t];
  }
  for (unsigned t = threadIdx.x; t < ne; t += blockDim.x){
    unsigned g = baseE + t;
    if (g < 8192u) eqbuf[img * 8192 + g] = le[t];
  }
}

// ---------- resolve exact ties at threshold via rank-selection ----------
__global__ void k_finalize(unsigned* __restrict__ cand, const unsigned* __restrict__ candCnt,
                           const unsigned* __restrict__ eqbuf, const unsigned* __restrict__ eqCnt,
                           const unsigned* __restrict__ need3){
  int img = blockIdx.x, tid = threadIdx.x;
  unsigned need = need3[img];
  unsigned ec = eqCnt[img]; if (ec > 8192u) ec = 8192u;
  unsigned base = candCnt[img];
  const unsigned* eq = eqbuf + img * 8192;
  unsigned* c = cand + img * 2048;
  if (need >= ec){
    for (unsigned t = tid; t < ec; t += 256) if (base + t < 2048u) c[base + t] = eq[t];
    return;
  }
  for (unsigned t = tid; t < ec; t += 256){
    unsigned v = eq[t], r = 0;
    for (unsigned s = 0; s < ec; s++) r += (eq[s] < v) ? 1u : 0u;
    if (r < need && base + r < 2048u) c[base + r] = v;
  }
}

// ---------- decode + clip + validity + key; count valid via wave ballot ----------
__global__ void k_decode(const float* __restrict__ cls, const float* __restrict__ reg,
                         const float* __restrict__ anch, const unsigned* __restrict__ cand,
                         float* __restrict__ boxTmp, ull* __restrict__ keys,
                         unsigned* __restrict__ nvalid){
  int s = blockIdx.x * blockDim.x + threadIdx.x;
  if (s >= NB * 2048) return;
  int img = s >> 11, slot = s & 2047;
  ull key = 0ull;
  float4 box = make_float4(0.f, 0.f, 0.f, 0.f);
  bool counted = false;
  if (slot < PRE){
    unsigned i = cand[img * 2048 + slot];
    if (i < NN){
      size_t gi = (size_t)img * NN + i;
      float4 a = ((const float4*)anch)[gi];
      float4 r = ((const float4*)reg)[gi];
      float sc = cls[gi];
      float aw = a.z - a.x, ah = a.w - a.y;
      float acx = a.x + 0.5f * aw, acy = a.y + 0.5f * ah;
      float pcx = r.x * aw + acx, pcy = r.y * ah + acy;
      float pw = expf(r.z) * aw, ph = expf(r.w) * ah;
      float x1 = pcx - 0.5f * pw, y1 = pcy - 0.5f * ph;
      float x2 = pcx + 0.5f * pw, y2 = pcy + 0.5f * ph;
      x1 = fminf(fmaxf(x1, 0.f), 1333.f); x2 = fminf(fmaxf(x2, 0.f), 1333.f);
      y1 = fminf(fmaxf(y1, 0.f), 800.f);  y2 = fminf(fmaxf(y2, 0.f), 800.f);
      bool valid = ((x2 - x1) >= 0.001f) && ((y2 - y1) >= 0.001f);
      unsigned up = valid ? f2u(sc) : 0u;
      key = ((ull)up << 32) | (ull)(0xFFFFFFFFu - i);   // score desc, index asc
      box = make_float4(x1, y1, x2, y2);
      counted = valid;
    }
  }
  keys[img * 2048 + slot] = key;
  ((float4*)boxTmp)[img * 2048 + slot] = box;
  ull bal = __ballot(counted);
  if ((threadIdx.x & 63) == 0 && bal)
    atomicAdd(&nvalid[img], (unsigned)__popcll(bal));
}

// ---------- rank-by-counting sort: rank = #{j : key_j > key_e}; scatter ----------
__global__ __launch_bounds__(256) void k_rank(const ull* __restrict__ keys,
                                              const float* __restrict__ boxTmp,
                                              float* __restrict__ sorted){
  __shared__ ull lk[2048];
  int img = blockIdx.y;
  int e = blockIdx.x * 256 + threadIdx.x;
  for (int t = threadIdx.x; t < 2048; t += 256) lk[t] = keys[img * 2048 + t];
  __syncthreads();
  ull me = lk[e];
  unsigned rank = 0;
  #pragma unroll 8
  for (int j = 0; j < 2048; j++) rank += (lk[j] > me) ? 1u : 0u;
  if (rank < PRE)
    ((float4*)sorted)[img * PRE + rank] = ((const float4*)boxTmp)[img * 2048 + e];
}

// ---------- suppression bitmask, PERMUTED layout: word w bit q <-> j = 32q+w ----------
__global__ __launch_bounds__(512) void k_mask(const float* __restrict__ sorted,
                                              const unsigned* __restrict__ nvalid,
                                              ull* __restrict__ mask, ull* __restrict__ bitmap){
  __shared__ float4 bx[PRE];
  __shared__ float  ar[PRE];
  __shared__ unsigned rowflag[16];
  int img = blockIdx.y, tid = threadIdx.x;
  if (tid < 16) rowflag[tid] = 0;
  for (int i = tid; i < PRE; i += 512){
    float4 b = ((const float4*)sorted)[img * PRE + i];
    bx[i] = b;
    ar[i] = (b.z - b.x) * (b.w - b.y);
  }
  __syncthreads();
  int row = blockIdx.x * 16 + (tid >> 5);
  int w = tid & 31;
  float4 bi = bx[row];
  float ai = ar[row];
  int qlo = (row >= w) ? (((row - w) >> 5) + 1) : 0;
  int qhi = ((PRE - 1 - w) >> 5) + 1;
  ull m = 0;
  for (int q = qlo; q < qhi; q++){
    int j = (q << 5) + w;
    float4 bj = bx[j];
    float xx1 = fmaxf(bi.x, bj.x), yy1 = fmaxf(bi.y, bj.y);
    float xx2 = fminf(bi.z, bj.z), yy2 = fminf(bi.w, bj.w);
    float ww = fmaxf(xx2 - xx1, 0.f), hh = fmaxf(yy2 - yy1, 0.f);
    float inter = ww * hh;
    float uni = ai + ar[j] - inter;
    if (inter / fmaxf(uni, 1e-8f) > 0.7f) m |= (1ull << q);   // exact div (bit-match)
  }
  mask[((size_t)(img * PRE + row)) * 32 + w] = m;
  if (m) atomicOr(&rowflag[tid >> 5], 1u);
  __syncthreads();
  if (tid < 16){
    int r = blockIdx.x * 16 + tid;
    if (rowflag[tid] && r < (int)nvalid[img])
      atomicOr(&bitmap[img * 32 + (r >> 6)], 1ull << (r & 63));
  }
}

// ---------- single-wave serial NMS: register remv + shfl test + prefetch ----------
// remv word w lives in lane w's register. Per iteration: uniform shfl of the
// owning word -> uniform branch -> predicated register OR. Next row's mask
// words and index are prefetched from LDS before the shfl-dependent chain, so
// the carried dependency is ~one bpermute + a few VALU (vs 2 LDS round-trips
// + ballot in the previous version).
__global__ __launch_bounds__(64) void k_nms(const ull* __restrict__ mask,
                                            const ull* __restrict__ bitmap,
                                            const unsigned* __restrict__ nvalid,
                                            const float* __restrict__ sorted,
                                            float* __restrict__ out){
  __shared__ unsigned rows[2048];
  __shared__ ull cache[192 * 32];
  __shared__ ull keepP[32];     // permuted keep: word w bit q -> j = 32q+w
  __shared__ ull keepLin[32];   // linear keep:   word w bit b -> i = 64w+b
  __shared__ unsigned cntArr[32], preArr[32];
  int img = blockIdx.x;
  int lane = threadIdx.x;       // 0..63, one wave

  // parallel bitmap decode (ascending row order preserved: word l covers
  // i in [64l, 64l+64), bits extracted ascending, written at prefix offset)
  ull bits = 0; unsigned wcnt = 0;
  if (lane < 32){ bits = bitmap[img * 32 + lane]; wcnt = (unsigned)__popcll(bits); }
  unsigned incl = wcnt;
  #pragma unroll
  for (int off = 1; off < 32; off <<= 1){
    unsigned v = __shfl_up(incl, off);
    if (lane >= off && lane < 32) incl += v;
  }
  if (lane < 32){
    ull b = bits; unsigned pos = incl - wcnt;
    while (b){
      int t = __ffsll(b) - 1;
      rows[pos++] = (unsigned)(lane * 64 + t);
      b &= b - 1;
    }
  }
  int m = __shfl((int)incl, 31);
  __syncthreads();

  ull myrem = 0;   // lane w (<32) holds permuted remv word w
  for (int base = 0; base < m; base += 192){
    int cnt = min(192, m - base);
    for (int t = lane; t < cnt * 32; t += 64){
      unsigned rr = rows[base + (t >> 5)];
      cache[t] = mask[((size_t)(img * PRE + rr)) * 32 + (t & 31)];
    }
    __syncthreads();
    ull cw = (lane < 32) ? cache[lane] : 0ull;
    unsigned ir = rows[base];
    for (int q = 0; q < cnt; q++){
      ull cwq = cw; unsigned i = ir;
      if (q + 1 < cnt){
        cw = (lane < 32) ? cache[((q + 1) << 5) + lane] : 0ull;
        ir = rows[base + q + 1];
      }
      int wi = i & 31, bi = i >> 5;          // permuted coords of row i
      ull rw = __shfl(myrem, wi);            // uniform src lane -> uniform value
      if (!((rw >> bi) & 1ull)) myrem |= cwq;  // uniform branch, register OR
    }
    __syncthreads();
  }

  int nv = (int)nvalid[img];
  if (lane < 32){
    int cnt2 = (nv > lane) ? (((nv - 1 - lane) >> 5) + 1) : 0;  // #valid q for word
    ull vm = (cnt2 >= 64) ? ~0ull : ((1ull << cnt2) - 1ull);
    keepP[lane] = (~myrem) & vm;
  }
  __syncthreads();
  if (lane < 32){   // permuted -> linear: bit kk of lin word wp is i = 64*wp + kk
    ull lin = 0;
    for (int kk = 0; kk < 64; kk++)
      lin |= ((keepP[kk & 31] >> (2 * lane + (kk >> 5))) & 1ull) << kk;
    keepLin[lane] = lin;
    cntArr[lane] = (unsigned)__popcll(lin);
  }
  __syncthreads();
  if (lane < 32){
    unsigned pre = 0;
    for (int w0 = 0; w0 < lane; w0++) pre += cntArr[w0];
    preArr[lane] = pre;
  }
  __syncthreads();
  for (int i = lane; i < PRE; i += 64){
    int w0 = i >> 6, b = i & 63;
    ull kw = keepLin[w0];
    if ((kw >> b) & 1ull){
      unsigned rank = preArr[w0] + (unsigned)__popcll(kw & ((1ull << b) - 1ull));
      if (rank < POST)
        ((float4*)out)[img * POST + rank] = ((const float4*)sorted)[img * PRE + i];
    }
  }
}

extern "C" void kernel_launch(void* const* d_in, const int* in_sizes, int n_in,
                              void* d_out, int out_size, void* d_ws, size_t ws_size,
                              hipStream_t stream){
  const float* cls  = (const float*)d_in[0];
  const float* reg  = (const float*)d_in[1];
  const float* anch = (const float*)d_in[2];
  float* out = (float*)d_out;
  char* ws = (char*)d_ws;

  unsigned* hist1   = (unsigned*)(ws + OFF_HIST1);
  unsigned* hist2   = (unsigned*)(ws + OFF_HIST2);
  unsigned* hist3   = (unsigned*)(ws + OFF_HIST3);
  unsigned* candCnt = (unsigned*)(ws + OFF_CANDCNT);
  unsigned* eqCnt   = (unsigned*)(ws + OFF_EQCNT);
  ull*      bitmap  = (ull*)     (ws + OFF_BITMAP);
  unsigned* b1      = (unsigned*)(ws + OFF_B1);
  unsigned* need1   = (unsigned*)(ws + OFF_NEED1);
  unsigned* b2      = (unsigned*)(ws + OFF_B2);
  unsigned* need2   = (unsigned*)(ws + OFF_NEED2);
  unsigned* b3      = (unsigned*)(ws + OFF_B3);
  unsigned* need3   = (unsigned*)(ws + OFF_NEED3);
  unsigned* nvalid  = (unsigned*)(ws + OFF_NVALID);
  unsigned* cand    = (unsigned*)(ws + OFF_CAND);
  unsigned* eqbuf   = (unsigned*)(ws + OFF_EQBUF);
  ull*      keys    = (ull*)     (ws + OFF_KEYS);
  float*    boxTmp  = (float*)   (ws + OFF_BOXTMP);
  float*    sorted  = (float*)   (ws + OFF_SORTED);
  ull*      mask    = (ull*)     (ws + OFF_MASK);

  hipMemsetAsync(ws, 0, ZERO_BYTES, stream);
  hipMemsetAsync(d_out, 0, (size_t)out_size * sizeof(float), stream);

  k_hist1<<<dim3(64, NB), 256, 0, stream>>>(cls, hist1);
  k_scan <<<NB, 256, 0, stream>>>(hist1, 1024, (const unsigned*)nullptr, 2000u, b1, need1);
  k_hist2<<<dim3(64, NB), 256, 0, stream>>>(cls, b1, hist2);
  k_scan <<<NB, 256, 0, stream>>>(hist2, 2048, need1, 0u, b2, need2);
  k_hist3<<<dim3(64, NB), 256, 0, stream>>>(cls, b1, b2, hist3);
  k_scan <<<NB, 256, 0, stream>>>(hist3, 2048, need2, 0u, b3, need3);
  k_compact<<<dim3(64, NB), 256, 0, stream>>>(cls, b1, b2, b3, cand, candCnt, eqbuf, eqCnt);
  k_finalize<<<NB, 256, 0, stream>>>(cand, candCnt, eqbuf, eqCnt, need3);
  k_decode<<<(NB * 2048) / 256, 256, 0, stream>>>(cls, reg, anch, cand, boxTmp, keys, nvalid);
  k_rank<<<dim3(8, NB), 256, 0, stream>>>(keys, boxTmp, sorted);
  k_mask<<<dim3(PRE / 16, NB), 512, 0, stream>>>(sorted, nvalid, mask, bitmap);
  k_nms<<<NB, 64, 0, stream>>>(mask, bitmap, nvalid, sorted, out);
}